// Round 6
// baseline (157.436 us; speedup 1.0000x reference)
//
#include <hip/hip_runtime.h>
#include <stdint.h>

// LowRankConv2d: out[b,o,h,w] = (1/9)*sum_{k,r,c} Hm[k,o,r]*G[k,r,c]*x[b,c,h+i-1,w+j-1] + bias[o]
// R6: perfectly balanced grids. R5's persistent grids had tail imbalance (fused1: 32/512
//     blocks did 4 items vs 3 -> +33% straggler time; stage2: 64/512 did 7 m-tiles vs 6 ->
//     +14%). Now fused1 = 784 blocks x 2 consecutive items, stage2 = 784 blocks x 4
//     consecutive m-tiles (also improves T9/out L1+L2 locality across the 3x3 tap window).

#define BATCH 16
#define CIN   256
#define COUT  256
#define RANK  32
#define HH    56
#define WW    56
#define SP    (HH*WW)        // 3136
#define YP    58
#define XP    58
#define PCELL (YP*XP)        // 3364
#define PLANE (BATCH*PCELL)

typedef __bf16 bf16x8 __attribute__((ext_vector_type(8)));
typedef float  f32x4  __attribute__((ext_vector_type(4)));

// ws layout (bytes):
//  T9   [9][16][58][58][32] bf16  = 31,002,624
//  G_bf [288][256] bf16           = 147,456
//  Hm_bf[9][256][32] bf16         = 147,456
#define OFF_T9 0
#define OFF_GB 31002624
#define OFF_HB (OFF_GB + 147456)

#define RING_U4 (9 * 16 * 228 * 4)   // border cells * 64B(=4 uint4)
#define PREP_N  (147456 + RING_U4)   // 278,784

__device__ __forceinline__ uint16_t bfbits(float f) {
  __bf16 h = (__bf16)f;
  return __builtin_bit_cast(uint16_t, h);
}

// weight casts + T9 border ring zero, one launch
__global__ __launch_bounds__(256) void k_prep(const float* __restrict__ G,
                                              const float* __restrict__ Hm,
                                              uint16_t* __restrict__ G_bf,
                                              uint16_t* __restrict__ Hm_bf,
                                              uint16_t* __restrict__ T9) {
  int i = blockIdx.x * 256 + threadIdx.x;
  if (i < 73728)  { G_bf[i] = bfbits(G[i]); return; }
  if (i < 147456) { Hm_bf[i - 73728] = bfbits(Hm[i - 73728]); return; }
  int j = i - 147456;
  if (j >= RING_U4) return;
  int v = j & 3, cell = j >> 2;
  int tb = cell / 228, c = cell % 228;
  int y, xx;
  if      (c < 58)  { y = 0;       xx = c;       }
  else if (c < 116) { y = 57;      xx = c - 58;  }
  else if (c < 172) { y = c - 115; xx = 0;       }
  else              { y = c - 171; xx = 57;      }
  uint16_t* base = T9 + ((size_t)tb * PCELL + y * XP + xx) * 32;
  uint4 z; z.x = z.y = z.z = z.w = 0u;
  ((uint4*)base)[v] = z;
}

// Fused transpose+cast+stage1: T9[tap][cell][r] = sum_c G[tap*32+r][c] * x[b][c][s]
// Block: 384 thr (6 waves); wave w holds G rows 48w..48w+47 reg-resident (24 frags).
// Grid 784, exactly 2 consecutive items (b, 32-pos chunk) per block (perfect balance).
__global__ __launch_bounds__(384, 3) void k_fused1(const float* __restrict__ x,
                                                   const uint16_t* __restrict__ G_bf,
                                                   uint16_t* __restrict__ T9) {
  __shared__ uint16_t xs[32 * 264];
  const int tid = threadIdx.x;
  const int wave = tid >> 6, lane = tid & 63;
  const int q = lane >> 4, t = lane & 15;

  bf16x8 A[3][8];
  {
    const uint16_t* gb = G_bf + (size_t)(wave * 48 + t) * CIN + q * 8;
#pragma unroll
    for (int i = 0; i < 3; ++i)
#pragma unroll
      for (int ks = 0; ks < 8; ++ks)
        A[i][ks] = *(const bf16x8*)(gb + (size_t)i * 16 * CIN + ks * 32);
  }

#pragma unroll 1
  for (int rep = 0; rep < 2; ++rep) {
    const int item = blockIdx.x * 2 + rep;
    const int b = item / 98, ch = item - b * 98;    // 98 chunks of 32 positions per batch

    // stage: 1024 units = (s 0..31, cg 0..31); unit loads 8 c-rows (s-coalesced), writes 16B
#pragma unroll 1
    for (int u = tid; u < 1024; u += 384) {
      const int s = u & 31, cg = u >> 5;
      const float* xr = x + ((size_t)(b * CIN + cg * 8)) * SP + ch * 32 + s;
      bf16x8 v;
#pragma unroll
      for (int e = 0; e < 8; ++e)
        ((__bf16*)&v)[e] = (__bf16)xr[(size_t)e * SP];
      *(bf16x8*)&xs[s * 264 + cg * 8] = v;
    }
    __syncthreads();

#pragma unroll 1
    for (int nt = 0; nt < 2; ++nt) {
      bf16x8 Bf[8];
#pragma unroll
      for (int ks = 0; ks < 8; ++ks)
        Bf[ks] = *(const bf16x8*)&xs[(nt * 16 + t) * 264 + ks * 32 + q * 8];

      f32x4 acc[3];
#pragma unroll
      for (int i = 0; i < 3; ++i) acc[i] = (f32x4){0.f, 0.f, 0.f, 0.f};
#pragma unroll
      for (int ks = 0; ks < 8; ++ks)
#pragma unroll
        for (int i = 0; i < 3; ++i)
          acc[i] = __builtin_amdgcn_mfma_f32_16x16x32_bf16(A[i][ks], Bf[ks], acc[i], 0, 0, 0);

      const int p = ch * 32 + nt * 16 + t;          // lane's store cell (D col = t)
      const int h = p / WW, w = p - (p / WW) * WW;
      const size_t cellbase = ((size_t)b * PCELL + (h + 1) * XP + (w + 1)) * 32;
#pragma unroll
      for (int i = 0; i < 3; ++i) {
        const int kr0 = wave * 48 + i * 16 + q * 4; // 4-run stays within one tap (4|32)
        const int tap = kr0 >> 5, r = kr0 & 31;
        uint2 pv;
        pv.x = (uint32_t)bfbits(acc[i][0]) | ((uint32_t)bfbits(acc[i][1]) << 16);
        pv.y = (uint32_t)bfbits(acc[i][2]) | ((uint32_t)bfbits(acc[i][3]) << 16);
        *(uint2*)(T9 + (size_t)tap * PLANE * 32 + cellbase + r) = pv;
      }
    }
    __syncthreads();
  }
}

// Stage 2: out[p][o] = (1/9)*sum_tap sum_r T9[tap][cell(p)+shift][r]*Hm[tap][o][r] + bias[o]
// Block: 512 thr (8 waves); wave w owns o in [32w, 32w+32): Bf[9][2] reg-resident (72 VGPR)
// -> 16 waves/CU. Grid 784, exactly 4 CONSECUTIVE m-tiles per block (balance + locality:
// overlapping tap rows hit L1, out writes form contiguous runs).
__global__ __launch_bounds__(512, 4) void k_stage2(const uint16_t* __restrict__ T9,
                                                   const uint16_t* __restrict__ Hm_bf,
                                                   const float* __restrict__ bias,
                                                   float* __restrict__ out) {
  const int wave = threadIdx.x >> 6, lane = threadIdx.x & 63;
  const int q = lane >> 4, t = lane & 15;

  bf16x8 Bf[9][2];
  float bv[2];
#pragma unroll
  for (int j = 0; j < 2; ++j) {
    const int o = wave * 32 + j * 16 + t;
    bv[j] = bias[o];
#pragma unroll
    for (int tap = 0; tap < 9; ++tap)
      Bf[tap][j] = *(const bf16x8*)(Hm_bf + ((size_t)(tap * COUT + o)) * RANK + q * 8);
  }

#pragma unroll 1
  for (int it = 0; it < 4; ++it) {
    const int mt = blockIdx.x * 4 + it;
    const int p0 = mt * 16;
    const int b = p0 / SP, s0 = p0 - b * SP;
    const int sa = s0 + t;
    const int ha = sa / WW, wa = sa - ha * WW;
    const uint16_t* abase = T9 + ((size_t)(b * PCELL + ha * XP + wa)) * 32 + q * 8;

    f32x4 acc[2];
    acc[0] = (f32x4){0.f, 0.f, 0.f, 0.f};
    acc[1] = (f32x4){0.f, 0.f, 0.f, 0.f};
#pragma unroll
    for (int tap = 0; tap < 9; ++tap) {
      const int di = tap / 3, dj = tap % 3;
      bf16x8 af = *(const bf16x8*)(abase + (size_t)tap * PLANE * 32 + (di * XP + dj) * 32);
      acc[0] = __builtin_amdgcn_mfma_f32_16x16x32_bf16(af, Bf[tap][0], acc[0], 0, 0, 0);
      acc[1] = __builtin_amdgcn_mfma_f32_16x16x32_bf16(af, Bf[tap][1], acc[1], 0, 0, 0);
    }

    const int sd = s0 + q * 4;                      // D rows = 4 consecutive positions
#pragma unroll
    for (int j = 0; j < 2; ++j) {
      const int o = wave * 32 + j * 16 + t;
      f32x4 v = acc[j] * (1.0f / 9.0f) + bv[j];
      *(f32x4*)(out + ((size_t)(b * COUT + o)) * SP + sd) = v;
    }
  }
}

extern "C" void kernel_launch(void* const* d_in, const int* in_sizes, int n_in,
                              void* d_out, int out_size, void* d_ws, size_t ws_size,
                              hipStream_t stream) {
  const float* x    = (const float*)d_in[0];
  const float* G    = (const float*)d_in[1];
  const float* Hm   = (const float*)d_in[2];
  const float* bias = (const float*)d_in[3];
  float* out = (float*)d_out;
  char* ws = (char*)d_ws;

  uint16_t* T9    = (uint16_t*)(ws + OFF_T9);
  uint16_t* G_bf  = (uint16_t*)(ws + OFF_GB);
  uint16_t* Hm_bf = (uint16_t*)(ws + OFF_HB);

  k_prep<<<PREP_N / 256, 256, 0, stream>>>(G, Hm, G_bf, Hm_bf, T9);
  k_fused1<<<784, 384, 0, stream>>>(x, G_bf, T9);
  k_stage2<<<784, 512, 0, stream>>>(T9, Hm_bf, bias, out);
}